// Round 1
// baseline (548.761 us; speedup 1.0000x reference)
//
#include <hip/hip_runtime.h>

#define SEQ   1024
#define BATCH 512
#define NC    48

__device__ __forceinline__ float rfl(float x) {
    return __int_as_float(__builtin_amdgcn_readfirstlane(__float_as_int(x)));
}

// One wave (64 lanes) per batch element. Lane j owns state j (j<48).
// Linear-domain forward recurrence with per-step scalar rescale:
//   z_new[j] = (sum_i z[i]*E[i][j]) * exp(s_t[j]) * m_hat
// where E = exp(T) is register-resident (48 VGPRs/lane, column j),
// z broadcast through LDS (12x ds_read_b128), m_hat = rcp(z[state0])
// computed off the critical path and folded into the next step's factor.
// Scale bookkeeping S (log2 domain) accounts exactly for every applied m_hat.
__global__ __launch_bounds__(64) void crf_fwd(
    const float* __restrict__ scores,   // [SEQ][BATCH][NC]
    const int*   __restrict__ target,   // [SEQ][BATCH]
    const int*   __restrict__ lengths,  // [BATCH]
    const float* __restrict__ trans,    // [NC][NC]
    float* __restrict__ out)            // [2*BATCH]: X, then X - logZ
{
    __shared__ float zbuf_s[64] __attribute__((aligned(16)));
    float* zbuf = zbuf_s;
    const float4* zv4 = reinterpret_cast<const float4*>(zbuf_s);

    const int b    = blockIdx.x;
    const int lane = threadIdx.x;
    const int jc   = (lane < NC) ? lane : (NC - 1);   // lanes 48-63 mirror state 47 (results masked out)
    const int L    = lengths[b];                       // uniform within block
    const float LOG2E = 1.4426950408889634f;
    const float LN2   = 0.6931471805599453f;
    const size_t TS = (size_t)BATCH * NC;              // t-stride in scores

    // ---- target path score X (parallel over t across lanes, then reduce) ----
    float x = 0.f;
    for (int t = lane; t < L; t += 64) {
        int cur = target[t * BATCH + b];
        float e = scores[(size_t)t * TS + (size_t)b * NC + cur];
        float tr = 0.f;
        if (t > 0) {
            int prev = target[(t - 1) * BATCH + b];
            tr = trans[prev * NC + cur];
        }
        x += e + tr;
    }
    #pragma unroll
    for (int k = 32; k >= 1; k >>= 1) x += __shfl_xor(x, k, 64);
    // x uniform across the wave now

    // ---- register-resident exp(T) column for this lane ----
    float Ecol[NC];
    #pragma unroll
    for (int i = 0; i < NC; ++i)
        Ecol[i] = __builtin_amdgcn_exp2f(trans[i * NC + jc] * LOG2E);

    // ---- t = 0 init: z = exp(s0 - s0[state0]); S tracks log2 of the factored-out scale ----
    const float* sp = scores + (size_t)b * NC + jc;
    float sv_init = sp[0];
    float s00 = rfl(sv_init);
    float z = __builtin_amdgcn_exp2f((sv_init - s00) * LOG2E);
    float S = s00 * LOG2E;
    zbuf[lane] = z;             // lanes 48-63 write slots 48-63: allocated, never read
    __syncthreads();

    // ---- software-pipelined score prefetch, depth 3 (~1000 cyc tolerance) ----
    float sv0 = sp[1 * TS];
    float sv1 = sp[2 * TS];
    float sv2 = sp[3 * TS];

    for (int t = 1; t < L; ++t) {
        // Scale prep for THIS step — runs in the shadow of the LDS roundtrip.
        // m_hat = rcp(z[state0] from previous step); exact bookkeeping: S -= log2(m_hat).
        float r    = rfl(z);
        float minv = __builtin_amdgcn_rcpf(r);
        S         -= __builtin_amdgcn_logf(minv);           // v_log_f32 = log2
        float esm  = __builtin_amdgcn_exp2f(sv0 * LOG2E) * minv;

        // rotate prefetch queue, issue load for t+3 (clamped; beyond-L values unused)
        sv0 = sv1; sv1 = sv2;
        int tp = t + 3; tp = (tp > SEQ - 1) ? (SEQ - 1) : tp;
        sv2 = sp[(size_t)tp * TS];

        // matvec: every lane reads the full 48-float z vector (broadcast reads,
        // conflict-free) against its register-held E column. 4 accumulators for ILP.
        float a0 = 0.f, a1 = 0.f, a2 = 0.f, a3 = 0.f;
        #pragma unroll
        for (int g = 0; g < 12; ++g) {
            float4 v = zv4[g];
            a0 = fmaf(v.x, Ecol[4*g+0], a0);
            a1 = fmaf(v.y, Ecol[4*g+1], a1);
            a2 = fmaf(v.z, Ecol[4*g+2], a2);
            a3 = fmaf(v.w, Ecol[4*g+3], a3);
        }
        float znew = ((a0 + a1) + (a2 + a3)) * esm;
        zbuf[lane] = znew;      // start next roundtrip ASAP
        z = znew;
        __syncthreads();        // single-wave block: compiler fence + cheap/elided barrier
    }

    // ---- finalize: logZ = ln2 * (log2(sum_j z_j) + S) ----
    float zs = (lane < NC) ? z : 0.f;
    #pragma unroll
    for (int k = 32; k >= 1; k >>= 1) zs += __shfl_xor(zs, k, 64);
    float logZ = (__builtin_amdgcn_logf(zs) + S) * LN2;

    if (lane == 0) {
        out[b]         = x;          // output 0: X
        out[BATCH + b] = x - logZ;   // output 1: X - logZ
    }
}

extern "C" void kernel_launch(void* const* d_in, const int* in_sizes, int n_in,
                              void* d_out, int out_size, void* d_ws, size_t ws_size,
                              hipStream_t stream) {
    const float* scores  = (const float*)d_in[0];
    const int*   target  = (const int*)d_in[1];
    const int*   lengths = (const int*)d_in[2];
    const float* trans   = (const float*)d_in[3];
    float* out = (float*)d_out;
    crf_fwd<<<BATCH, 64, 0, stream>>>(scores, target, lengths, trans, out);
}

// Round 2
// 541.467 us; speedup vs baseline: 1.0135x; 1.0135x over previous
//
#include <hip/hip_runtime.h>

#define SEQ   1024
#define BATCH 512
#define NC    48

__device__ __forceinline__ float rfl(float x) {
    return __int_as_float(__builtin_amdgcn_readfirstlane(__float_as_int(x)));
}

// One wave (64 lanes) per batch element. Lane j owns state j (j<48).
// Linear-domain forward recurrence with per-step scalar rescale:
//   z_new[j] = (sum_i z[i]*E[i][j]) * exp(s_t[j]) * m_hat
// E = exp(T) register-resident (48 VGPRs/lane, column j); z broadcast via LDS
// (12x ds_read_b128, conflict-free broadcast); m_hat = rcp(z[state0]) folded
// into the next step's factor; exact log2-domain scale bookkeeping in S.
//
// NO __syncthreads(): the block is a single wave. Same-wave LDS write->read
// ordering is guaranteed by the in-order DS pipe + compiler lgkmcnt waits
// (zbuf accesses alias, so program order is preserved). Crucially this avoids
// the barrier's s_waitcnt vmcnt(0), which in R1 drained the score prefetch
// every iteration and exposed ~900 cyc of HBM latency per step (1007 cyc/step
// measured vs ~330 modeled).
__global__ __launch_bounds__(64) void crf_fwd(
    const float* __restrict__ scores,   // [SEQ][BATCH][NC]
    const int*   __restrict__ target,   // [SEQ][BATCH]
    const int*   __restrict__ lengths,  // [BATCH]
    const float* __restrict__ trans,    // [NC][NC]
    float* __restrict__ out)            // [2*BATCH]: X, then X - logZ
{
    __shared__ float zbuf_s[64] __attribute__((aligned(16)));
    float* zbuf = zbuf_s;
    const float4* zv4 = reinterpret_cast<const float4*>(zbuf_s);

    const int b    = blockIdx.x;
    const int lane = threadIdx.x;
    const int jc   = (lane < NC) ? lane : (NC - 1);   // lanes 48-63 mirror state 47 (masked out)
    const int L    = lengths[b];                       // uniform within block
    const float LOG2E = 1.4426950408889634f;
    const float LN2   = 0.6931471805599453f;
    const size_t TS = (size_t)BATCH * NC;              // t-stride in scores

    // ---- target path score X (parallel over t across lanes, then reduce) ----
    float x = 0.f;
    for (int t = lane; t < L; t += 64) {
        int cur = target[t * BATCH + b];
        float e = scores[(size_t)t * TS + (size_t)b * NC + cur];
        float tr = 0.f;
        if (t > 0) {
            int prev = target[(t - 1) * BATCH + b];
            tr = trans[prev * NC + cur];
        }
        x += e + tr;
    }
    #pragma unroll
    for (int k = 32; k >= 1; k >>= 1) x += __shfl_xor(x, k, 64);
    // x uniform across the wave now

    // ---- register-resident exp(T) column for this lane ----
    float Ecol[NC];
    #pragma unroll
    for (int i = 0; i < NC; ++i)
        Ecol[i] = __builtin_amdgcn_exp2f(trans[i * NC + jc] * LOG2E);

    // ---- t = 0 init: z = exp(s0 - s0[state0]); S tracks log2 of factored-out scale ----
    const float* sp = scores + (size_t)b * NC + jc;
    float sv_init = sp[0];
    float s00 = rfl(sv_init);
    float z = __builtin_amdgcn_exp2f((sv_init - s00) * LOG2E);
    float S = s00 * LOG2E;
    zbuf[lane] = z;             // same-wave LDS ordering; no barrier needed

    // ---- software-pipelined score prefetch, depth 4 (~1400 cyc tolerance) ----
    float sv0 = sp[1 * TS];
    float sv1 = sp[2 * TS];
    float sv2 = sp[3 * TS];
    float sv3 = sp[4 * TS];

    for (int t = 1; t < L; ++t) {
        // Scale prep for THIS step — runs in the shadow of the LDS roundtrip.
        float r    = rfl(z);
        float minv = __builtin_amdgcn_rcpf(r);
        S         -= __builtin_amdgcn_logf(minv);           // v_log_f32 = log2
        float esm  = __builtin_amdgcn_exp2f(sv0 * LOG2E) * minv;

        // rotate prefetch queue, issue load for t+4 (clamped; beyond-L values unused)
        sv0 = sv1; sv1 = sv2; sv2 = sv3;
        int tp = t + 4; tp = (tp > SEQ - 1) ? (SEQ - 1) : tp;
        sv3 = sp[(size_t)tp * TS];

        // matvec: every lane reads the full 48-float z vector (broadcast reads,
        // conflict-free) against its register-held E column. 4 accumulators for ILP.
        float a0 = 0.f, a1 = 0.f, a2 = 0.f, a3 = 0.f;
        #pragma unroll
        for (int g = 0; g < 12; ++g) {
            float4 v = zv4[g];
            a0 = fmaf(v.x, Ecol[4*g+0], a0);
            a1 = fmaf(v.y, Ecol[4*g+1], a1);
            a2 = fmaf(v.z, Ecol[4*g+2], a2);
            a3 = fmaf(v.w, Ecol[4*g+3], a3);
        }
        float znew = ((a0 + a1) + (a2 + a3)) * esm;
        zbuf[lane] = znew;      // start next roundtrip ASAP (same-wave ordering)
        z = znew;
    }

    // ---- finalize: logZ = ln2 * (log2(sum_j z_j) + S) ----
    float zs = (lane < NC) ? z : 0.f;
    #pragma unroll
    for (int k = 32; k >= 1; k >>= 1) zs += __shfl_xor(zs, k, 64);
    float logZ = (__builtin_amdgcn_logf(zs) + S) * LN2;

    if (lane == 0) {
        out[b]         = x;          // output 0: X
        out[BATCH + b] = x - logZ;   // output 1: X - logZ
    }
}

extern "C" void kernel_launch(void* const* d_in, const int* in_sizes, int n_in,
                              void* d_out, int out_size, void* d_ws, size_t ws_size,
                              hipStream_t stream) {
    const float* scores  = (const float*)d_in[0];
    const int*   target  = (const int*)d_in[1];
    const int*   lengths = (const int*)d_in[2];
    const float* trans   = (const float*)d_in[3];
    float* out = (float*)d_out;
    crf_fwd<<<BATCH, 64, 0, stream>>>(scores, target, lengths, trans, out);
}

// Round 3
// 541.187 us; speedup vs baseline: 1.0140x; 1.0005x over previous
//
#include <hip/hip_runtime.h>

#define SEQ   1024
#define BATCH 512
#define NC    48

__device__ __forceinline__ float rfl(float x) {
    return __int_as_float(__builtin_amdgcn_readfirstlane(__float_as_int(x)));
}

// One wave (64 lanes) per batch element. Lane j owns state j (j<48).
// Linear-domain forward recurrence with per-step scalar rescale:
//   z_new[j] = (sum_i z[i]*E[i][j]) * exp(s_t[j]) * m_hat
// E = exp(T) held in 12 NAMED float4 registers (no array => no scratch spill;
// R1/R2 showed VGPR_Count=56-60, i.e. the 48-float Ecol array was NOT
// register-promoted and每 iter re-loaded from scratch — suspected 600 cyc/iter).
// z broadcast via LDS (12x ds_read_b128, conflict-free broadcast); m_hat =
// rcp(z[state0]) folded into the next step's factor; exact log2 bookkeeping S.
// No __syncthreads(): single-wave block, same-wave DS-pipe ordering suffices.
__global__ __launch_bounds__(64, 1) void crf_fwd(
    const float* __restrict__ scores,   // [SEQ][BATCH][NC]
    const int*   __restrict__ target,   // [SEQ][BATCH]
    const int*   __restrict__ lengths,  // [BATCH]
    const float* __restrict__ trans,    // [NC][NC]
    float* __restrict__ out)            // [2*BATCH]: X, then X - logZ
{
    __shared__ float zbuf_s[64] __attribute__((aligned(16)));
    float* zbuf = zbuf_s;
    const float4* zv4 = reinterpret_cast<const float4*>(zbuf_s);

    const int b    = blockIdx.x;
    const int lane = threadIdx.x;
    const int jc   = (lane < NC) ? lane : (NC - 1);   // lanes 48-63 mirror state 47 (masked out)
    const int L    = lengths[b];                       // uniform within block
    const float LOG2E = 1.4426950408889634f;
    const float LN2   = 0.6931471805599453f;
    const size_t TS = (size_t)BATCH * NC;              // t-stride in scores

    // ---- target path score X (parallel over t across lanes, then reduce) ----
    // unroll 4: iterations are independent -> their target->score dependent
    // load chains overlap instead of serializing.
    float x = 0.f;
    #pragma unroll 4
    for (int t = lane; t < L; t += 64) {
        int cur = target[t * BATCH + b];
        float e = scores[(size_t)t * TS + (size_t)b * NC + cur];
        float tr = 0.f;
        if (t > 0) {
            int prev = target[(t - 1) * BATCH + b];
            tr = trans[prev * NC + cur];
        }
        x += e + tr;
    }
    #pragma unroll
    for (int k = 32; k >= 1; k >>= 1) x += __shfl_xor(x, k, 64);
    // x uniform across the wave now

    // ---- E = exp(T) column jc, in 12 named float4 registers (spill-proof) ----
    #define MKE(g) float4 E##g = make_float4( \
        __builtin_amdgcn_exp2f(trans[(4*(g)+0)*NC + jc] * LOG2E), \
        __builtin_amdgcn_exp2f(trans[(4*(g)+1)*NC + jc] * LOG2E), \
        __builtin_amdgcn_exp2f(trans[(4*(g)+2)*NC + jc] * LOG2E), \
        __builtin_amdgcn_exp2f(trans[(4*(g)+3)*NC + jc] * LOG2E))
    MKE(0); MKE(1); MKE(2);  MKE(3);
    MKE(4); MKE(5); MKE(6);  MKE(7);
    MKE(8); MKE(9); MKE(10); MKE(11);
    #undef MKE

    // ---- t = 0 init: z = exp(s0 - s0[state0]); S tracks log2 of factored-out scale ----
    const float* sp = scores + (size_t)b * NC + jc;
    float sv_init = sp[0];
    float s00 = rfl(sv_init);
    float z = __builtin_amdgcn_exp2f((sv_init - s00) * LOG2E);
    float S = s00 * LOG2E;
    zbuf[lane] = z;             // same-wave LDS ordering; no barrier needed

    // ---- software-pipelined score prefetch, depth 4 ----
    float sv0 = sp[1 * TS];
    float sv1 = sp[2 * TS];
    float sv2 = sp[3 * TS];
    float sv3 = sp[4 * TS];

    for (int t = 1; t < L; ++t) {
        // Scale prep — in the shadow of the LDS roundtrip.
        float r    = rfl(z);
        float minv = __builtin_amdgcn_rcpf(r);
        S         -= __builtin_amdgcn_logf(minv);           // v_log_f32 = log2
        float esm  = __builtin_amdgcn_exp2f(sv0 * LOG2E) * minv;

        // rotate prefetch queue, issue load for t+4 (clamped; beyond-L unused)
        sv0 = sv1; sv1 = sv2; sv2 = sv3;
        int tp = t + 4; tp = (tp > SEQ - 1) ? (SEQ - 1) : tp;
        sv3 = sp[(size_t)tp * TS];

        // Load all 12 z-quads first (fine-grained lgkmcnt waits), then FMA.
        float4 v0 = zv4[0],  v1 = zv4[1],  v2  = zv4[2],  v3  = zv4[3];
        float4 v4 = zv4[4],  v5 = zv4[5],  v6  = zv4[6],  v7  = zv4[7];
        float4 v8 = zv4[8],  v9 = zv4[9],  v10 = zv4[10], v11 = zv4[11];

        // 8 accumulators: each chains 6 FMAs (24 cyc) instead of 12 (48 cyc).
        float a0 = 0.f, a1 = 0.f, a2 = 0.f, a3 = 0.f;
        float a4 = 0.f, a5 = 0.f, a6 = 0.f, a7 = 0.f;
        #define G_EVEN(vv, EE) { a0 = fmaf(vv.x, EE.x, a0); a1 = fmaf(vv.y, EE.y, a1); \
                                 a2 = fmaf(vv.z, EE.z, a2); a3 = fmaf(vv.w, EE.w, a3); }
        #define G_ODD(vv, EE)  { a4 = fmaf(vv.x, EE.x, a4); a5 = fmaf(vv.y, EE.y, a5); \
                                 a6 = fmaf(vv.z, EE.z, a6); a7 = fmaf(vv.w, EE.w, a7); }
        G_EVEN(v0,  E0);  G_ODD(v1,  E1);
        G_EVEN(v2,  E2);  G_ODD(v3,  E3);
        G_EVEN(v4,  E4);  G_ODD(v5,  E5);
        G_EVEN(v6,  E6);  G_ODD(v7,  E7);
        G_EVEN(v8,  E8);  G_ODD(v9,  E9);
        G_EVEN(v10, E10); G_ODD(v11, E11);
        #undef G_EVEN
        #undef G_ODD

        float znew = (((a0 + a4) + (a1 + a5)) + ((a2 + a6) + (a3 + a7))) * esm;
        zbuf[lane] = znew;      // start next roundtrip ASAP (same-wave ordering)
        z = znew;
    }

    // ---- finalize: logZ = ln2 * (log2(sum_j z_j) + S) ----
    float zs = (lane < NC) ? z : 0.f;
    #pragma unroll
    for (int k = 32; k >= 1; k >>= 1) zs += __shfl_xor(zs, k, 64);
    float logZ = (__builtin_amdgcn_logf(zs) + S) * LN2;

    if (lane == 0) {
        out[b]         = x;          // output 0: X
        out[BATCH + b] = x - logZ;   // output 1: X - logZ
    }
}

extern "C" void kernel_launch(void* const* d_in, const int* in_sizes, int n_in,
                              void* d_out, int out_size, void* d_ws, size_t ws_size,
                              hipStream_t stream) {
    const float* scores  = (const float*)d_in[0];
    const int*   target  = (const int*)d_in[1];
    const int*   lengths = (const int*)d_in[2];
    const float* trans   = (const float*)d_in[3];
    float* out = (float*)d_out;
    crf_fwd<<<BATCH, 64, 0, stream>>>(scores, target, lengths, trans, out);
}

// Round 4
// 385.675 us; speedup vs baseline: 1.4229x; 1.4032x over previous
//
#include <hip/hip_runtime.h>

#define SEQ   1024
#define BATCH 512
#define NC    48
#define CH    8

__device__ __forceinline__ float rfl(float x) {
    return __int_as_float(__builtin_amdgcn_readfirstlane(__float_as_int(x)));
}

// One wave per batch element. Lane j owns state j (j<48).
// z_new[j] = (sum_i z[i]*E[i][j]) * exp(s_t[j]) * rcp(z_prev[0]); exact log2
// bookkeeping in S. E = exp(T) column per lane, PINNED into 48 VGPRs via an
// opaque asm barrier — R1-R3 showed VGPR_Count=60 (too small for 48 live E
// values): the compiler was REMATERIALIZING E (trans reload + v_exp) inside
// the loop, ~650 cyc/step. Scores are staged in register chunks of CH=8
// (double-buffered A/B, fully unrolled) so vmem waits only occur at chunk
// boundaries where loads are ~2600 cyc old (free). No __syncthreads: single
// wave; DS-pipe ordering + lgkmcnt suffice for the zbuf roundtrip.
__global__ __launch_bounds__(64, 1) void crf_fwd(
    const float* __restrict__ scores,   // [SEQ][BATCH][NC]
    const int*   __restrict__ target,   // [SEQ][BATCH]
    const int*   __restrict__ lengths,  // [BATCH]
    const float* __restrict__ trans,    // [NC][NC]
    float* __restrict__ out)            // [2*BATCH]: X, then X - logZ
{
    __shared__ float zbuf_s[64] __attribute__((aligned(16)));
    float* zbuf = zbuf_s;
    const float4* zv4 = reinterpret_cast<const float4*>(zbuf_s);

    const int b    = blockIdx.x;
    const int lane = threadIdx.x;
    const int jc   = (lane < NC) ? lane : (NC - 1);   // lanes 48-63 mirror (masked out)
    const int L    = lengths[b];                       // uniform within block
    const float LOG2E = 1.4426950408889634f;
    const float LN2   = 0.6931471805599453f;
    const size_t TS = (size_t)BATCH * NC;
    const float* sp = scores + (size_t)b * NC + jc;

    // ---- register staging buffers + first two chunks in flight ----
    float A[CH], B[CH];
    #define PREFETCH(buf, tbase) do { \
        _Pragma("unroll") \
        for (int k_ = 0; k_ < CH; ++k_) { \
            int tt_ = (tbase) + k_; if (tt_ > SEQ - 1) tt_ = SEQ - 1; \
            (buf)[k_] = sp[(size_t)tt_ * TS]; \
        } } while (0)
    PREFETCH(A, 0);
    PREFETCH(B, CH);

    // ---- target path score X (parallel over t, then reduce) ----
    float x = 0.f;
    #pragma unroll 4
    for (int t = lane; t < L; t += 64) {
        int cur = target[t * BATCH + b];
        float e = scores[(size_t)t * TS + (size_t)b * NC + cur];
        float tr = 0.f;
        if (t > 0) {
            int prev = target[(t - 1) * BATCH + b];
            tr = trans[prev * NC + cur];
        }
        x += e + tr;
    }
    #pragma unroll
    for (int k = 32; k >= 1; k >>= 1) x += __shfl_xor(x, k, 64);

    // ---- E = exp(T) column jc: 48 scalars, pinned in VGPRs (no remat) ----
    #define DECLE(i) float e##i = __builtin_amdgcn_exp2f(trans[(i)*NC + jc] * LOG2E); \
                     asm("" : "+v"(e##i));
    DECLE(0)  DECLE(1)  DECLE(2)  DECLE(3)  DECLE(4)  DECLE(5)  DECLE(6)  DECLE(7)
    DECLE(8)  DECLE(9)  DECLE(10) DECLE(11) DECLE(12) DECLE(13) DECLE(14) DECLE(15)
    DECLE(16) DECLE(17) DECLE(18) DECLE(19) DECLE(20) DECLE(21) DECLE(22) DECLE(23)
    DECLE(24) DECLE(25) DECLE(26) DECLE(27) DECLE(28) DECLE(29) DECLE(30) DECLE(31)
    DECLE(32) DECLE(33) DECLE(34) DECLE(35) DECLE(36) DECLE(37) DECLE(38) DECLE(39)
    DECLE(40) DECLE(41) DECLE(42) DECLE(43) DECLE(44) DECLE(45) DECLE(46) DECLE(47)
    #undef DECLE

    // ---- t = 0 init ----
    float sv_init = A[0];
    float s00 = rfl(sv_init);
    float z = __builtin_amdgcn_exp2f((sv_init - s00) * LOG2E);
    float S = s00 * LOG2E;
    zbuf[lane] = z;

    // ---- one recurrence step (compile-time s index into reg chunk) ----
    #define STEP(buf, sidx, tbase) do { \
        const int t_ = (tbase) + (sidx); \
        float r_    = rfl(z); \
        float minv_ = __builtin_amdgcn_rcpf(r_); \
        float esm_  = __builtin_amdgcn_exp2f((buf)[sidx] * LOG2E) * minv_; \
        float4 v0_ = zv4[0], v1_ = zv4[1], v2_  = zv4[2],  v3_  = zv4[3]; \
        float4 v4_ = zv4[4], v5_ = zv4[5], v6_  = zv4[6],  v7_  = zv4[7]; \
        float4 v8_ = zv4[8], v9_ = zv4[9], v10_ = zv4[10], v11_ = zv4[11]; \
        float a0=0.f,a1=0.f,a2=0.f,a3=0.f,a4=0.f,a5=0.f,a6=0.f,a7=0.f; \
        a0=fmaf(v0_.x,e0,a0);  a1=fmaf(v0_.y,e1,a1);  a2=fmaf(v0_.z,e2,a2);  a3=fmaf(v0_.w,e3,a3); \
        a4=fmaf(v1_.x,e4,a4);  a5=fmaf(v1_.y,e5,a5);  a6=fmaf(v1_.z,e6,a6);  a7=fmaf(v1_.w,e7,a7); \
        a0=fmaf(v2_.x,e8,a0);  a1=fmaf(v2_.y,e9,a1);  a2=fmaf(v2_.z,e10,a2); a3=fmaf(v2_.w,e11,a3); \
        a4=fmaf(v3_.x,e12,a4); a5=fmaf(v3_.y,e13,a5); a6=fmaf(v3_.z,e14,a6); a7=fmaf(v3_.w,e15,a7); \
        a0=fmaf(v4_.x,e16,a0); a1=fmaf(v4_.y,e17,a1); a2=fmaf(v4_.z,e18,a2); a3=fmaf(v4_.w,e19,a3); \
        a4=fmaf(v5_.x,e20,a4); a5=fmaf(v5_.y,e21,a5); a6=fmaf(v5_.z,e22,a6); a7=fmaf(v5_.w,e23,a7); \
        a0=fmaf(v6_.x,e24,a0); a1=fmaf(v6_.y,e25,a1); a2=fmaf(v6_.z,e26,a2); a3=fmaf(v6_.w,e27,a3); \
        a4=fmaf(v7_.x,e28,a4); a5=fmaf(v7_.y,e29,a5); a6=fmaf(v7_.z,e30,a6); a7=fmaf(v7_.w,e31,a7); \
        a0=fmaf(v8_.x,e32,a0); a1=fmaf(v8_.y,e33,a1); a2=fmaf(v8_.z,e34,a2); a3=fmaf(v8_.w,e35,a3); \
        a4=fmaf(v9_.x,e36,a4); a5=fmaf(v9_.y,e37,a5); a6=fmaf(v9_.z,e38,a6); a7=fmaf(v9_.w,e39,a7); \
        a0=fmaf(v10_.x,e40,a0);a1=fmaf(v10_.y,e41,a1);a2=fmaf(v10_.z,e42,a2);a3=fmaf(v10_.w,e43,a3); \
        a4=fmaf(v11_.x,e44,a4);a5=fmaf(v11_.y,e45,a5);a6=fmaf(v11_.z,e46,a6);a7=fmaf(v11_.w,e47,a7); \
        float sum_  = (((a0+a4)+(a1+a5)) + ((a2+a6)+(a3+a7))); \
        float znew_ = sum_ * esm_; \
        float Snew_ = S - __builtin_amdgcn_logf(minv_); \
        if (t_ < L) { z = znew_; S = Snew_; }  /* uniform freeze == t_mask */ \
        zbuf[lane] = z; \
    } while (0)

    #define CHUNK8(buf, tbase) do { \
        STEP(buf,0,tbase); STEP(buf,1,tbase); STEP(buf,2,tbase); STEP(buf,3,tbase); \
        STEP(buf,4,tbase); STEP(buf,5,tbase); STEP(buf,6,tbase); STEP(buf,7,tbase); \
    } while (0)

    // prologue: steps 1..7 from chunk 0
    STEP(A,1,0); STEP(A,2,0); STEP(A,3,0); STEP(A,4,0);
    STEP(A,5,0); STEP(A,6,0); STEP(A,7,0);

    // main: alternate buffers; prefetch next chunk before processing current
    int t0 = CH;
    while (t0 < L) {
        PREFETCH(A, t0 + CH);
        CHUNK8(B, t0);
        t0 += CH;
        if (t0 >= L) break;
        PREFETCH(B, t0 + CH);
        CHUNK8(A, t0);
        t0 += CH;
    }
    #undef STEP
    #undef CHUNK8
    #undef PREFETCH

    // ---- finalize ----
    float zs = (lane < NC) ? z : 0.f;
    #pragma unroll
    for (int k = 32; k >= 1; k >>= 1) zs += __shfl_xor(zs, k, 64);
    float logZ = (__builtin_amdgcn_logf(zs) + S) * LN2;

    if (lane == 0) {
        out[b]         = x;          // output 0: X
        out[BATCH + b] = x - logZ;   // output 1: X - logZ
    }
}

extern "C" void kernel_launch(void* const* d_in, const int* in_sizes, int n_in,
                              void* d_out, int out_size, void* d_ws, size_t ws_size,
                              hipStream_t stream) {
    const float* scores  = (const float*)d_in[0];
    const int*   target  = (const int*)d_in[1];
    const int*   lengths = (const int*)d_in[2];
    const float* trans   = (const float*)d_in[3];
    float* out = (float*)d_out;
    crf_fwd<<<BATCH, 64, 0, stream>>>(scores, target, lengths, trans, out);
}

// Round 5
// 347.071 us; speedup vs baseline: 1.5811x; 1.1112x over previous
//
#include <hip/hip_runtime.h>

#define SEQ   1024
#define BATCH 512
#define NC    48
#define CH    8

__device__ __forceinline__ float rfl(float x) {
    return __int_as_float(__builtin_amdgcn_readfirstlane(__float_as_int(x)));
}
__device__ __forceinline__ float rlane(float x, int l) {
    return __int_as_float(__builtin_amdgcn_readlane(__float_as_int(x), l));
}

// One wave per batch element. Lane j owns state j (j<48).
// z_new[j] = (sum_i z[i]*E[i][j]) * exp2(s_t[j]*log2e - ex) where ex is the
// binary exponent of z_prev[0] (exact power-of-2 rescale; S += ex, exact).
//
// R4 lesson: per-step cost was 643 cyc, of which only ~136 was VALU — the
// rest was the LDS write->12x ds_read_b128 broadcast roundtrip. R5 removes
// LDS from the recurrence entirely: the all-to-all broadcast is done with
// 48x v_readlane (z lane i -> SGPR) + 48x v_fma with SGPR operand. The
// critical path is pure VALU issue (~110 instr), no memory latency.
// E = exp(T) stays pinned in 48 VGPRs (R4: pinning beat rematerialization).
// Scores staged in register chunks (CH=8, A/B double buffer) so vmem waits
// land on ~2600-cycle-old loads.
__global__ __launch_bounds__(64, 1) void crf_fwd(
    const float* __restrict__ scores,   // [SEQ][BATCH][NC]
    const int*   __restrict__ target,   // [SEQ][BATCH]
    const int*   __restrict__ lengths,  // [BATCH]
    const float* __restrict__ trans,    // [NC][NC]
    float* __restrict__ out)            // [2*BATCH]: X, then X - logZ
{
    const int b    = blockIdx.x;
    const int lane = threadIdx.x;
    const int jc   = (lane < NC) ? lane : (NC - 1);   // lanes 48-63 mirror col 47 (never read)
    const int L    = lengths[b];                       // uniform within block
    const float LOG2E = 1.4426950408889634f;
    const float LN2   = 0.6931471805599453f;
    const size_t TS = (size_t)BATCH * NC;
    const float* sp = scores + (size_t)b * NC + jc;

    // ---- register staging buffers + first two chunks in flight ----
    float A[CH], B[CH];
    #define PREFETCH(buf, tbase) do { \
        _Pragma("unroll") \
        for (int k_ = 0; k_ < CH; ++k_) { \
            int tt_ = (tbase) + k_; if (tt_ > SEQ - 1) tt_ = SEQ - 1; \
            (buf)[k_] = sp[(size_t)tt_ * TS]; \
        } } while (0)
    PREFETCH(A, 0);
    PREFETCH(B, CH);

    // ---- target path score X (parallel over t, then reduce) ----
    float x = 0.f;
    #pragma unroll 4
    for (int t = lane; t < L; t += 64) {
        int cur = target[t * BATCH + b];
        float e = scores[(size_t)t * TS + (size_t)b * NC + cur];
        float tr = 0.f;
        if (t > 0) {
            int prev = target[(t - 1) * BATCH + b];
            tr = trans[prev * NC + cur];
        }
        x += e + tr;
    }
    #pragma unroll
    for (int k = 32; k >= 1; k >>= 1) x += __shfl_xor(x, k, 64);

    // ---- E = exp(T) column jc: 48 scalars, pinned in VGPRs (no remat) ----
    #define DECLE(i) float e##i = __builtin_amdgcn_exp2f(trans[(i)*NC + jc] * LOG2E); \
                     asm("" : "+v"(e##i));
    DECLE(0)  DECLE(1)  DECLE(2)  DECLE(3)  DECLE(4)  DECLE(5)  DECLE(6)  DECLE(7)
    DECLE(8)  DECLE(9)  DECLE(10) DECLE(11) DECLE(12) DECLE(13) DECLE(14) DECLE(15)
    DECLE(16) DECLE(17) DECLE(18) DECLE(19) DECLE(20) DECLE(21) DECLE(22) DECLE(23)
    DECLE(24) DECLE(25) DECLE(26) DECLE(27) DECLE(28) DECLE(29) DECLE(30) DECLE(31)
    DECLE(32) DECLE(33) DECLE(34) DECLE(35) DECLE(36) DECLE(37) DECLE(38) DECLE(39)
    DECLE(40) DECLE(41) DECLE(42) DECLE(43) DECLE(44) DECLE(45) DECLE(46) DECLE(47)
    #undef DECLE

    // ---- t = 0 init ----
    float sv_init = A[0];
    float s00 = rfl(sv_init);
    float z = __builtin_amdgcn_exp2f((sv_init - s00) * LOG2E);
    float S = s00 * LOG2E;

    // 8 readlane-broadcasts + 8 SGPR*VGPR FMAs
    #define G8(l0,l1,l2,l3,l4,l5,l6,l7, ea,eb,ec,ed,ee,ef,eg,eh) { \
        float s0_=rlane(z,l0), s1_=rlane(z,l1), s2_=rlane(z,l2), s3_=rlane(z,l3); \
        float s4_=rlane(z,l4), s5_=rlane(z,l5), s6_=rlane(z,l6), s7_=rlane(z,l7); \
        a0=fmaf(s0_,ea,a0); a1=fmaf(s1_,eb,a1); a2=fmaf(s2_,ec,a2); a3=fmaf(s3_,ed,a3); \
        a4=fmaf(s4_,ee,a4); a5=fmaf(s5_,ef,a5); a6=fmaf(s6_,eg,a6); a7=fmaf(s7_,eh,a7); }

    // ---- one recurrence step; broadcast via readlane, exact pow2 rescale ----
    #define STEP(buf, sidx, tbase) do { \
        const int t_ = (tbase) + (sidx); \
        float r_   = rfl(z); \
        int   ex_  = ((__float_as_int(r_) >> 23) & 255) - 126;  /* scalar bit ops */ \
        float exf_ = (float)ex_; \
        float esm_ = __builtin_amdgcn_exp2f(fmaf((buf)[sidx], LOG2E, -exf_)); \
        float a0=0.f,a1=0.f,a2=0.f,a3=0.f,a4=0.f,a5=0.f,a6=0.f,a7=0.f; \
        G8( 0, 1, 2, 3, 4, 5, 6, 7,  e0 ,e1 ,e2 ,e3 ,e4 ,e5 ,e6 ,e7 ) \
        G8( 8, 9,10,11,12,13,14,15,  e8 ,e9 ,e10,e11,e12,e13,e14,e15) \
        G8(16,17,18,19,20,21,22,23,  e16,e17,e18,e19,e20,e21,e22,e23) \
        G8(24,25,26,27,28,29,30,31,  e24,e25,e26,e27,e28,e29,e30,e31) \
        G8(32,33,34,35,36,37,38,39,  e32,e33,e34,e35,e36,e37,e38,e39) \
        G8(40,41,42,43,44,45,46,47,  e40,e41,e42,e43,e44,e45,e46,e47) \
        float sum_  = (((a0+a4)+(a1+a5)) + ((a2+a6)+(a3+a7))); \
        float znew_ = sum_ * esm_; \
        float Snew_ = S + exf_; \
        if (t_ < L) { z = znew_; S = Snew_; }  /* uniform freeze == t_mask */ \
    } while (0)

    #define CHUNK8(buf, tbase) do { \
        STEP(buf,0,tbase); STEP(buf,1,tbase); STEP(buf,2,tbase); STEP(buf,3,tbase); \
        STEP(buf,4,tbase); STEP(buf,5,tbase); STEP(buf,6,tbase); STEP(buf,7,tbase); \
    } while (0)

    // prologue: steps 1..7 from chunk 0
    STEP(A,1,0); STEP(A,2,0); STEP(A,3,0); STEP(A,4,0);
    STEP(A,5,0); STEP(A,6,0); STEP(A,7,0);

    // main: alternate buffers; prefetch next chunk before processing current
    int t0 = CH;
    while (t0 < L) {
        PREFETCH(A, t0 + CH);
        CHUNK8(B, t0);
        t0 += CH;
        if (t0 >= L) break;
        PREFETCH(B, t0 + CH);
        CHUNK8(A, t0);
        t0 += CH;
    }
    #undef STEP
    #undef CHUNK8
    #undef PREFETCH
    #undef G8

    // ---- finalize: logZ = ln2 * (log2(sum_j z_j) + S) ----
    float zs = (lane < NC) ? z : 0.f;
    #pragma unroll
    for (int k = 32; k >= 1; k >>= 1) zs += __shfl_xor(zs, k, 64);
    float logZ = (__builtin_amdgcn_logf(zs) + S) * LN2;

    if (lane == 0) {
        out[b]         = x;          // output 0: X
        out[BATCH + b] = x - logZ;   // output 1: X - logZ
    }
}

extern "C" void kernel_launch(void* const* d_in, const int* in_sizes, int n_in,
                              void* d_out, int out_size, void* d_ws, size_t ws_size,
                              hipStream_t stream) {
    const float* scores  = (const float*)d_in[0];
    const int*   target  = (const int*)d_in[1];
    const int*   lengths = (const int*)d_in[2];
    const float* trans   = (const float*)d_in[3];
    float* out = (float*)d_out;
    crf_fwd<<<BATCH, 64, 0, stream>>>(scores, target, lengths, trans, out);
}